// Round 5
// baseline (170.928 us; speedup 1.0000x reference)
//
#include <hip/hip_runtime.h>

// out[e] = dot(h[src[e]], h[dst[e]]), D=128, h f32.
// Pass 1: per-row int8 quantization into TWO compact half-row arrays:
//         q_lo = feats 0..63 (64B/row, 6.4MB), q_hi = feats 64..127.
// Pass 2: gather kernel A: out[e]  = fs * dot_lo(e)   (footprint 6.4MB)
// Pass 3: gather kernel B: out[e] += fs * dot_hi(e)   (footprint 6.4MB)
//
// Rounds 2-4 post-mortem: batching(b8), sched_barrier, and hand-pinned
// inline-asm loads with exact vmcnt ALL left gather dur bit-identical at
// 48.9us -> the gather is insensitive to per-wave scheduling; the chip is
// saturated at the outstanding-miss / fabric-service level (156MB @3.4TB/s).
// The remaining lever is the TRAFFIC term: q footprint 12.8MB vs 4MB
// per-XCD L2 gives 33% miss. Temporal D-split halves the resident
// footprint per pass (6.4MB) -> predicted miss ~15-22%, FETCH 156->~125MB.
// EA requests are 32/64B granular, so 64B half-rows waste no line bytes.
// Falsifier: FETCH >=150MB & dur >=48us => random-gather roofline.

#define D_FEAT 128

__device__ __forceinline__ int dot4_i8(unsigned a, unsigned b, int c) {
#if __has_builtin(__builtin_amdgcn_sdot4)
    return __builtin_amdgcn_sdot4((int)a, (int)b, c, false);
#else
    int r = c;
#pragma unroll
    for (int i = 0; i < 4; ++i) {
        int ai = (int)(a << (24 - 8 * i)) >> 24;
        int bi = (int)(b << (24 - 8 * i)) >> 24;
        r += ai * bi;
    }
    return r;
#endif
}

__device__ __forceinline__ unsigned pack4(int b0, int b1, int b2, int b3) {
    return (unsigned)(b0 & 0xff) | ((unsigned)(b1 & 0xff) << 8) |
           ((unsigned)(b2 & 0xff) << 16) | ((unsigned)(b3 & 0xff) << 24);
}

// Quantize rows into split half-row layout: q_lo[row*64..] = feats 0..63,
// q_hi[row*64..] = feats 64..127. 16 lanes/row, one uint2 (8 feats) each.
__global__ __launch_bounds__(256) void quantize_rows_split(
    const float* __restrict__ h,
    signed char* __restrict__ q_lo,
    signed char* __restrict__ q_hi,
    float* __restrict__ scale,
    int n_rows)
{
    int tid  = blockIdx.x * blockDim.x + threadIdx.x;
    int row  = tid >> 4;
    int lane = tid & 15;
    if (row >= n_rows) return;

    const float4* p = (const float4*)(h + (long)row * D_FEAT) + lane * 2;
    float4 x = p[0];
    float4 y = p[1];

    float m = fabsf(x.x);
    m = fmaxf(m, fabsf(x.y)); m = fmaxf(m, fabsf(x.z)); m = fmaxf(m, fabsf(x.w));
    m = fmaxf(m, fabsf(y.x)); m = fmaxf(m, fabsf(y.y));
    m = fmaxf(m, fabsf(y.z)); m = fmaxf(m, fabsf(y.w));

    m = fmaxf(m, __shfl_xor(m, 8));
    m = fmaxf(m, __shfl_xor(m, 4));
    m = fmaxf(m, __shfl_xor(m, 2));
    m = fmaxf(m, __shfl_xor(m, 1));

    float inv = (m > 0.f) ? (127.f / m) : 0.f;

    int b0 = (int)rintf(x.x * inv), b1 = (int)rintf(x.y * inv);
    int b2 = (int)rintf(x.z * inv), b3 = (int)rintf(x.w * inv);
    int b4 = (int)rintf(y.x * inv), b5 = (int)rintf(y.y * inv);
    int b6 = (int)rintf(y.z * inv), b7 = (int)rintf(y.w * inv);

    uint2 o;
    o.x = pack4(b0, b1, b2, b3);
    o.y = pack4(b4, b5, b6, b7);

    // lane 0..7 hold feats 0..63 -> q_lo; lane 8..15 -> q_hi.
    signed char* dstp = (lane < 8)
        ? (q_lo + (long)row * 64 + (long)lane * 8)
        : (q_hi + (long)row * 64 + (long)(lane - 8) * 8);
    *(uint2*)dstp = o;

    if (lane == 0) scale[row] = m * (1.f / 127.f);
}

// Gather over ONE half (64B rows). 4 edges per 8-lane subgroup (the proven
// b4 structure); lane loads uint2 (8B) of each operand row-half.
// accumulate=0: out[e] = fs*dot ; accumulate=1: out[e] += fs*dot.
__global__ __launch_bounds__(256) void edge_dot_i8_half(
    const signed char* __restrict__ qh,
    const float* __restrict__ scale,
    const int* __restrict__ src,
    const int* __restrict__ dst,
    float* __restrict__ out,
    int n_edges,
    int accumulate)
{
    int tid  = blockIdx.x * blockDim.x + threadIdx.x;
    int sub  = tid >> 3;          // subgroup id
    int lane = tid & 7;
    int e0   = sub * 4;
    if (e0 >= n_edges) return;

    int e1 = min(e0 + 1, n_edges - 1);
    int e2 = min(e0 + 2, n_edges - 1);
    int e3 = min(e0 + 3, n_edges - 1);

    int s0 = src[e0], s1 = src[e1], s2 = src[e2], s3 = src[e3];
    int d0 = dst[e0], d1 = dst[e1], d2 = dst[e2], d3 = dst[e3];

    // 8 half-row loads (8B each) issued before any use.
    const uint2* qb = (const uint2*)qh;   // half-row = 8 uint2
    uint2 a0 = qb[(long)s0 * 8 + lane];
    uint2 a1 = qb[(long)s1 * 8 + lane];
    uint2 a2 = qb[(long)s2 * 8 + lane];
    uint2 a3 = qb[(long)s3 * 8 + lane];
    uint2 b0 = qb[(long)d0 * 8 + lane];
    uint2 b1 = qb[(long)d1 * 8 + lane];
    uint2 b2 = qb[(long)d2 * 8 + lane];
    uint2 b3 = qb[(long)d3 * 8 + lane];

    float fs0 = scale[s0] * scale[d0];
    float fs1 = scale[s1] * scale[d1];
    float fs2 = scale[s2] * scale[d2];
    float fs3 = scale[s3] * scale[d3];

    int i0 = dot4_i8(a0.x, b0.x, 0);
    i0 = dot4_i8(a0.y, b0.y, i0);
    int i1 = dot4_i8(a1.x, b1.x, 0);
    i1 = dot4_i8(a1.y, b1.y, i1);
    int i2 = dot4_i8(a2.x, b2.x, 0);
    i2 = dot4_i8(a2.y, b2.y, i2);
    int i3 = dot4_i8(a3.x, b3.x, 0);
    i3 = dot4_i8(a3.y, b3.y, i3);

    i0 += __shfl_xor(i0, 4); i0 += __shfl_xor(i0, 2); i0 += __shfl_xor(i0, 1);
    i1 += __shfl_xor(i1, 4); i1 += __shfl_xor(i1, 2); i1 += __shfl_xor(i1, 1);
    i2 += __shfl_xor(i2, 4); i2 += __shfl_xor(i2, 2); i2 += __shfl_xor(i2, 1);
    i3 += __shfl_xor(i3, 4); i3 += __shfl_xor(i3, 2); i3 += __shfl_xor(i3, 1);

    if (lane == 0) {
        float v0 = (float)i0 * fs0;
        float v1 = (float)i1 * fs1;
        float v2 = (float)i2 * fs2;
        float v3 = (float)i3 * fs3;
        if (accumulate) {
            v0 += out[e0];
            if (e0 + 1 < n_edges) v1 += out[e0 + 1];
            if (e0 + 2 < n_edges) v2 += out[e0 + 2];
            if (e0 + 3 < n_edges) v3 += out[e0 + 3];
        }
        out[e0] = v0;
        if (e0 + 1 < n_edges) out[e0 + 1] = v1;
        if (e0 + 2 < n_edges) out[e0 + 2] = v2;
        if (e0 + 3 < n_edges) out[e0 + 3] = v3;
    }
}

// Last-resort f32 direct gather (workspace too small).
__global__ __launch_bounds__(256) void edge_dot_f32(
    const float* __restrict__ h,
    const int* __restrict__ src,
    const int* __restrict__ dst,
    float* __restrict__ out,
    int n_edges)
{
    int tid  = blockIdx.x * blockDim.x + threadIdx.x;
    int e    = tid >> 4;
    int lane = tid & 15;
    if (e >= n_edges) return;

    long srow = (long)src[e] * D_FEAT;
    long drow = (long)dst[e] * D_FEAT;

    const float4* hs = (const float4*)(h + srow) + lane * 2;
    const float4* hd = (const float4*)(h + drow) + lane * 2;
    float4 a0 = hs[0], a1 = hs[1], b0 = hd[0], b1 = hd[1];

    float acc = a0.x * b0.x + a0.y * b0.y + a0.z * b0.z + a0.w * b0.w
              + a1.x * b1.x + a1.y * b1.y + a1.z * b1.z + a1.w * b1.w;

    acc += __shfl_xor(acc, 8);
    acc += __shfl_xor(acc, 4);
    acc += __shfl_xor(acc, 2);
    acc += __shfl_xor(acc, 1);

    if (lane == 0) out[e] = acc;
}

extern "C" void kernel_launch(void* const* d_in, const int* in_sizes, int n_in,
                              void* d_out, int out_size, void* d_ws, size_t ws_size,
                              hipStream_t stream)
{
    const float* h   = (const float*)d_in[0];
    const int*   src = (const int*)d_in[1];
    const int*   dst = (const int*)d_in[2];
    float*       out = (float*)d_out;

    int n_edges = in_sizes[1];
    int n_feat  = in_sizes[0];
    int n_rows  = n_feat / D_FEAT;

    size_t half_sz = (size_t)n_rows * 64;                  // per-half bytes
    size_t sc_off  = (2 * half_sz + 255) & ~(size_t)255;   // == n_feat rounded
    size_t need    = sc_off + (size_t)n_rows * sizeof(float);

    int block = 256;

    if (ws_size >= need) {
        signed char* q_lo  = (signed char*)d_ws;
        signed char* q_hi  = (signed char*)d_ws + half_sz;
        float*       scale = (float*)((char*)d_ws + sc_off);

        int grid_quant = (n_rows * 16 + block - 1) / block;
        int n_sub      = (n_edges + 3) / 4;
        long threads   = (long)n_sub * 8;
        int grid_dot   = (int)((threads + block - 1) / block);

        quantize_rows_split<<<grid_quant, block, 0, stream>>>(h, q_lo, q_hi, scale, n_rows);
        edge_dot_i8_half<<<grid_dot, block, 0, stream>>>(q_lo, scale, src, dst, out, n_edges, 0);
        edge_dot_i8_half<<<grid_dot, block, 0, stream>>>(q_hi, scale, src, dst, out, n_edges, 1);
    } else {
        int grid_dot = (n_edges * 16 + block - 1) / block;
        edge_dot_f32<<<grid_dot, block, 0, stream>>>(h, src, dst, out, n_edges);
    }
}

// Round 6
// 137.077 us; speedup vs baseline: 1.2469x; 1.2469x over previous
//
#include <hip/hip_runtime.h>

// out[e] = dot(h[src[e]], h[dst[e]]), D=128, h f32.
// Pass 1: per-row int8 quantization (q = rint(x*127/rowmax), scale = rowmax/127).
// Pass 2: unsorted gather with 4-edge batching per 8-lane subgroup.
//
// FINAL structure (reverted to the best-measured kernel, 137.6us e2e).
// Session evidence for why this is the floor:
//  - R2 (b8 batching), R3 (sched_barrier pin), R4 (inline-asm loads + exact
//    vmcnt): gather dur bit-identical 48.9us in all three -> per-wave MLP
//    is NOT the limiter (chip-level miss concurrency already saturated).
//  - R5 (temporal D-split, 6.4MB footprint/pass): 2x row-touches -> 1.8x
//    gather time; per-touch cost nearly footprint-invariant.
//  => gather time ~ 7.6ns per random row-touch (131G touches/s chip-wide);
//     6.4M touches -> ~49us. Sort/binning/int4 all measured or bounded
//     net-negative in this or the prior session.
// e2e = ~49 (gather floor) + ~15 (quantize, near stream floor) + ~45
//       (harness workspace re-poison fill, not controllable) + gaps.

#define D_FEAT 128

__device__ __forceinline__ int dot4_i8(unsigned a, unsigned b, int c) {
#if __has_builtin(__builtin_amdgcn_sdot4)
    return __builtin_amdgcn_sdot4((int)a, (int)b, c, false);
#else
    int r = c;
#pragma unroll
    for (int i = 0; i < 4; ++i) {
        int ai = (int)(a << (24 - 8 * i)) >> 24;
        int bi = (int)(b << (24 - 8 * i)) >> 24;
        r += ai * bi;
    }
    return r;
#endif
}

__device__ __forceinline__ unsigned pack4(int b0, int b1, int b2, int b3) {
    return (unsigned)(b0 & 0xff) | ((unsigned)(b1 & 0xff) << 8) |
           ((unsigned)(b2 & 0xff) << 16) | ((unsigned)(b3 & 0xff) << 24);
}

__global__ __launch_bounds__(256) void quantize_rows(
    const float* __restrict__ h,
    signed char* __restrict__ q,
    float* __restrict__ scale,
    int n_rows)
{
    int tid  = blockIdx.x * blockDim.x + threadIdx.x;
    int row  = tid >> 4;
    int lane = tid & 15;
    if (row >= n_rows) return;

    const float4* p = (const float4*)(h + (long)row * D_FEAT) + lane * 2;
    float4 x = p[0];
    float4 y = p[1];

    float m = fabsf(x.x);
    m = fmaxf(m, fabsf(x.y)); m = fmaxf(m, fabsf(x.z)); m = fmaxf(m, fabsf(x.w));
    m = fmaxf(m, fabsf(y.x)); m = fmaxf(m, fabsf(y.y));
    m = fmaxf(m, fabsf(y.z)); m = fmaxf(m, fabsf(y.w));

    m = fmaxf(m, __shfl_xor(m, 8));
    m = fmaxf(m, __shfl_xor(m, 4));
    m = fmaxf(m, __shfl_xor(m, 2));
    m = fmaxf(m, __shfl_xor(m, 1));

    float inv = (m > 0.f) ? (127.f / m) : 0.f;

    int b0 = (int)rintf(x.x * inv), b1 = (int)rintf(x.y * inv);
    int b2 = (int)rintf(x.z * inv), b3 = (int)rintf(x.w * inv);
    int b4 = (int)rintf(y.x * inv), b5 = (int)rintf(y.y * inv);
    int b6 = (int)rintf(y.z * inv), b7 = (int)rintf(y.w * inv);

    uint2 o;
    o.x = pack4(b0, b1, b2, b3);
    o.y = pack4(b4, b5, b6, b7);
    ((uint2*)(q + (long)row * D_FEAT))[lane] = o;

    if (lane == 0) scale[row] = m * (1.f / 127.f);
}

// Unsorted gather, 4 edges per 8-lane subgroup.
__global__ __launch_bounds__(256) void edge_dot_i8_b4(
    const signed char* __restrict__ q,
    const float* __restrict__ scale,
    const int* __restrict__ src,
    const int* __restrict__ dst,
    float* __restrict__ out,
    int n_edges)
{
    int tid  = blockIdx.x * blockDim.x + threadIdx.x;
    int sub  = tid >> 3;          // subgroup id
    int lane = tid & 7;
    int e0   = sub * 4;
    if (e0 >= n_edges) return;

    // Clamp indices for the (rare) tail so all loads stay in-bounds and
    // non-divergent; only the stores are guarded.
    int e1 = min(e0 + 1, n_edges - 1);
    int e2 = min(e0 + 2, n_edges - 1);
    int e3 = min(e0 + 3, n_edges - 1);

    int s0 = src[e0], s1 = src[e1], s2 = src[e2], s3 = src[e3];
    int d0 = dst[e0], d1 = dst[e1], d2 = dst[e2], d3 = dst[e3];

    // Issue all 8 row loads before any use.
    uint4 qa0 = ((const uint4*)(q + (long)s0 * D_FEAT))[lane];
    uint4 qa1 = ((const uint4*)(q + (long)s1 * D_FEAT))[lane];
    uint4 qa2 = ((const uint4*)(q + (long)s2 * D_FEAT))[lane];
    uint4 qa3 = ((const uint4*)(q + (long)s3 * D_FEAT))[lane];
    uint4 qb0 = ((const uint4*)(q + (long)d0 * D_FEAT))[lane];
    uint4 qb1 = ((const uint4*)(q + (long)d1 * D_FEAT))[lane];
    uint4 qb2 = ((const uint4*)(q + (long)d2 * D_FEAT))[lane];
    uint4 qb3 = ((const uint4*)(q + (long)d3 * D_FEAT))[lane];

    float fs0 = scale[s0] * scale[d0];
    float fs1 = scale[s1] * scale[d1];
    float fs2 = scale[s2] * scale[d2];
    float fs3 = scale[s3] * scale[d3];

    int i0 = dot4_i8(qa0.x, qb0.x, 0);
    i0 = dot4_i8(qa0.y, qb0.y, i0);
    i0 = dot4_i8(qa0.z, qb0.z, i0);
    i0 = dot4_i8(qa0.w, qb0.w, i0);

    int i1 = dot4_i8(qa1.x, qb1.x, 0);
    i1 = dot4_i8(qa1.y, qb1.y, i1);
    i1 = dot4_i8(qa1.z, qb1.z, i1);
    i1 = dot4_i8(qa1.w, qb1.w, i1);

    int i2 = dot4_i8(qa2.x, qb2.x, 0);
    i2 = dot4_i8(qa2.y, qb2.y, i2);
    i2 = dot4_i8(qa2.z, qb2.z, i2);
    i2 = dot4_i8(qa2.w, qb2.w, i2);

    int i3 = dot4_i8(qa3.x, qb3.x, 0);
    i3 = dot4_i8(qa3.y, qb3.y, i3);
    i3 = dot4_i8(qa3.z, qb3.z, i3);
    i3 = dot4_i8(qa3.w, qb3.w, i3);

    i0 += __shfl_xor(i0, 4); i0 += __shfl_xor(i0, 2); i0 += __shfl_xor(i0, 1);
    i1 += __shfl_xor(i1, 4); i1 += __shfl_xor(i1, 2); i1 += __shfl_xor(i1, 1);
    i2 += __shfl_xor(i2, 4); i2 += __shfl_xor(i2, 2); i2 += __shfl_xor(i2, 1);
    i3 += __shfl_xor(i3, 4); i3 += __shfl_xor(i3, 2); i3 += __shfl_xor(i3, 1);

    if (lane == 0) {
        out[e0] = (float)i0 * fs0;
        if (e0 + 1 < n_edges) out[e0 + 1] = (float)i1 * fs1;
        if (e0 + 2 < n_edges) out[e0 + 2] = (float)i2 * fs2;
        if (e0 + 3 < n_edges) out[e0 + 3] = (float)i3 * fs3;
    }
}

// Last-resort f32 direct gather (workspace too small).
__global__ __launch_bounds__(256) void edge_dot_f32(
    const float* __restrict__ h,
    const int* __restrict__ src,
    const int* __restrict__ dst,
    float* __restrict__ out,
    int n_edges)
{
    int tid  = blockIdx.x * blockDim.x + threadIdx.x;
    int e    = tid >> 4;
    int lane = tid & 15;
    if (e >= n_edges) return;

    long srow = (long)src[e] * D_FEAT;
    long drow = (long)dst[e] * D_FEAT;

    const float4* hs = (const float4*)(h + srow) + lane * 2;
    const float4* hd = (const float4*)(h + drow) + lane * 2;
    float4 a0 = hs[0], a1 = hs[1], b0 = hd[0], b1 = hd[1];

    float acc = a0.x * b0.x + a0.y * b0.y + a0.z * b0.z + a0.w * b0.w
              + a1.x * b1.x + a1.y * b1.y + a1.z * b1.z + a1.w * b1.w;

    acc += __shfl_xor(acc, 8);
    acc += __shfl_xor(acc, 4);
    acc += __shfl_xor(acc, 2);
    acc += __shfl_xor(acc, 1);

    if (lane == 0) out[e] = acc;
}

extern "C" void kernel_launch(void* const* d_in, const int* in_sizes, int n_in,
                              void* d_out, int out_size, void* d_ws, size_t ws_size,
                              hipStream_t stream)
{
    const float* h   = (const float*)d_in[0];
    const int*   src = (const int*)d_in[1];
    const int*   dst = (const int*)d_in[2];
    float*       out = (float*)d_out;

    int n_edges = in_sizes[1];
    int n_feat  = in_sizes[0];
    int n_rows  = n_feat / D_FEAT;

    size_t q_sz   = (size_t)n_feat;
    size_t sc_off = (q_sz + 255) & ~(size_t)255;
    size_t need   = sc_off + (size_t)n_rows * sizeof(float);

    int block = 256;

    if (ws_size >= need) {
        signed char* q     = (signed char*)d_ws;
        float*       scale = (float*)((char*)d_ws + sc_off);

        int grid_quant = (n_rows * 16 + block - 1) / block;
        int n_sub      = (n_edges + 3) / 4;
        int grid_dot   = (n_sub * 8 + block - 1) / block;

        quantize_rows<<<grid_quant, block, 0, stream>>>(h, q, scale, n_rows);
        edge_dot_i8_b4<<<grid_dot, block, 0, stream>>>(q, scale, src, dst, out, n_edges);
    } else {
        int grid_dot = (n_edges * 16 + block - 1) / block;
        edge_dot_f32<<<grid_dot, block, 0, stream>>>(h, src, dst, out, n_edges);
    }
}